// Round 3
// baseline (482.729 us; speedup 1.0000x reference)
//
#include <hip/hip_runtime.h>

#define N_NODES 50000
#define N_EDGES 600000
#define N_GRAPHS 64
#define N_TILES (N_EDGES / 16)   // 37500 wave-tiles
#define NPART 196                // ceil(50000/256) scan partials
#define EDGE_GRID 2048           // 8 blocks/CU (16KB LDS) -> 32 waves/CU

// constants
#define INV_LIN_IN  0.35355339059327373f   // 1/sqrt(8)
#define INV_LIN_OUT 0.25f                  // 1/sqrt(16)
#define C_INV_S3    0.5773502691896258f    // 1/sqrt(3)
#define C_INV_S2    0.7071067811865476f    // 1/sqrt(2)
#define C_NORM_S    0.04419417382415922f   // 1/sqrt(512)
#define C_NORM_V    0.036084391824351615f  // 1/sqrt(768)

// fp16 overflow guard: features entering layers 1,2 are scaled by ALPHA after
// the gate; the inverse (1/ALPHA^2 = 1024) is folded into those layers' weights.
// TP is bilinear so this is exact. Keeps layer-3 fp16 products ~56 max vs 65504.
#define ALPHA      0.03125f                // 1/32
#define W_UNSCALE  1024.0f                 // 1/ALPHA^2

typedef __attribute__((ext_vector_type(8))) _Float16 h16x8;
typedef __attribute__((ext_vector_type(4))) _Float16 h16x4;
typedef __attribute__((ext_vector_type(2))) _Float16 h16x2;
typedef __attribute__((ext_vector_type(4))) float f32x4;

// ==================== sort edges by destination (row); pack (row,col) in one int ====
__global__ void hist_kernel(const int* __restrict__ row, int* __restrict__ counts) {
    int e = blockIdx.x * 256 + threadIdx.x;
    if (e < N_EDGES) atomicAdd(&counts[row[e]], 1);
}

__global__ void scan_part_kernel(const int* __restrict__ counts, int* __restrict__ partial) {
    __shared__ int sm[256];
    int t = threadIdx.x;
    int i = blockIdx.x * 256 + t;
    sm[t] = (i < N_NODES) ? counts[i] : 0;
    __syncthreads();
    for (int s = 128; s > 0; s >>= 1) {
        if (t < s) sm[t] += sm[t + s];
        __syncthreads();
    }
    if (t == 0) partial[blockIdx.x] = sm[0];
}

// scan_final with the partial-prefix folded in (replaces scan_partials_kernel):
// each block reduces partial[0..blockIdx) in a second shared array.
__global__ void scan_final_kernel(const int* __restrict__ counts,
                                  const int* __restrict__ partial,
                                  int* __restrict__ cursor) {
    __shared__ int sm[256];
    __shared__ int sm2[256];
    int t = threadIdx.x;
    int i = blockIdx.x * 256 + t;
    int v = (i < N_NODES) ? counts[i] : 0;
    sm[t] = v;
    sm2[t] = (t < NPART && t < blockIdx.x) ? partial[t] : 0;
    __syncthreads();
    // tree-reduce sm2 -> sum of partial[0..blockIdx)
    for (int s = 128; s > 0; s >>= 1) {
        if (t < s) sm2[t] += sm2[t + s];
        __syncthreads();
    }
    int base = sm2[0];
    // inclusive scan of counts within block
    for (int s = 1; s < 256; s <<= 1) {
        int add = (t >= s) ? sm[t - s] : 0;
        __syncthreads();
        sm[t] += add;
        __syncthreads();
    }
    if (i < N_NODES) cursor[i] = sm[t] - v + base;   // exclusive offsets
}

__global__ void scatter_kernel(const int* __restrict__ row, const int* __restrict__ col,
                               int* __restrict__ cursor, int* __restrict__ sortedRC) {
    int e = blockIdx.x * 256 + threadIdx.x;
    if (e < N_EDGES) {
        int n = row[e];
        int pos = atomicAdd(&cursor[n], 1);
        sortedRC[pos] = n | (col[e] << 16);   // node ids < 50000 < 65536
    }
}

// -------------------- fused init: proj (fp16 out) + weight swizzle (fp16) +
// counts-zero + energy-zero + acc-zero (replaces hipMemsetAsync)
__global__ void init_kernel(const float* __restrict__ x,
                            const float* __restrict__ w_in0,
                            const float* __restrict__ w_in1,
                            const float* __restrict__ tp_w,
                            h16x4* __restrict__ featH,
                            _Float16* __restrict__ wh,
                            int* __restrict__ counts,
                            float* __restrict__ energy,
                            float4* __restrict__ acc) {
    int gid = blockIdx.x * 256 + threadIdx.x;

    if (gid < 64) energy[gid] = 0.f;
    if (gid < N_NODES) counts[gid] = 0;

    // zero the f32 accumulator: 800k float4 over 61440 threads (grid-stride)
    for (int idx = gid; idx < N_NODES * 16; idx += 61440)
        acc[idx] = make_float4(0.f, 0.f, 0.f, 0.f);

    if (gid < 3 * 20480) {   // weight swizzle -> fp16 (one-time cost)
        int i = gid;
        int j    = i & 7;
        int t1   = i >> 3;
        int lane = t1 & 63;
        int t2   = t1 >> 6;
        int c    = t2 & 7;
        int t3   = t2 >> 3;
        int slot = t3 % 5;
        int l    = t3 / 5;
        int p = (slot == 0) ? 1 : (slot == 1) ? 2 : (slot == 2) ? 4 : (slot == 3) ? 0 : 3;
        int kk = c * 32 + (lane >> 4) * 8 + j;
        int u = kk >> 4, v = kk & 15, n = lane & 15;
        float scale;
        if      (p == 0) scale = C_NORM_S;
        else if (p == 3) scale = C_INV_S3 * C_NORM_S;
        else if (p == 4) scale = C_INV_S2 * C_NORM_V;
        else             scale = C_NORM_V;   // p==1, p==2
        if (l > 0) scale *= W_UNSCALE;       // undo ALPHA^2 feature pre-scale
        float val = tp_w[(size_t)(l * 5 + p) * 4096 + u * 256 + v * 16 + n] * scale;
        wh[i] = (_Float16)val;
    }

    if (gid < N_NODES) {     // input projection -> fp16 features (layer-0: unscaled)
        const float* xp = x + (size_t)gid * 32;
        float xs[8], xvx[8], xvy[8], xvz[8];
#pragma unroll
        for (int u = 0; u < 8; ++u) xs[u] = xp[u];
#pragma unroll
        for (int u = 0; u < 8; ++u) {
            xvx[u] = xp[8 + 3 * u + 0];
            xvy[u] = xp[8 + 3 * u + 1];
            xvz[u] = xp[8 + 3 * u + 2];
        }
#pragma unroll
        for (int w = 0; w < 16; ++w) {
            float s = 0.f, vx = 0.f, vy = 0.f, vz = 0.f;
#pragma unroll
            for (int u = 0; u < 8; ++u) {
                float a0 = w_in0[u * 16 + w];
                float a1 = w_in1[u * 16 + w];
                s  += xs[u]  * a0;
                vx += xvx[u] * a1;
                vy += xvy[u] * a1;
                vz += xvz[u] * a1;
            }
            h16x4 o;
            o.x = (_Float16)(s  * INV_LIN_IN);
            o.y = (_Float16)(vx * INV_LIN_IN);
            o.z = (_Float16)(vy * INV_LIN_IN);
            o.w = (_Float16)(vz * INV_LIN_IN);
            featH[(size_t)gid * 16 + w] = o;
        }
    }
}

// -------------------- edge tensor product (fp16): persistent waves, W1/W2 in
// LDS (16KB -> 8 blocks/CU = 100% wave cap), W4/W0/W3 from global (L1-hot);
// z-formation fully in packed v_pk_*_f16; unroll 4 for the load-hoisting window.
__global__ __launch_bounds__(256, 8)
void edge_tp_kernel(const h16x4* __restrict__ feat,
                    float* __restrict__ out,          // [N][16][4] f32 accum
                    const int* __restrict__ sortedRC,
                    const _Float16* __restrict__ wh) {
    __shared__ h16x8 sW[1024];   // 16 KB: paths {1,2}

    const int t = threadIdx.x;
    {
        const int4* src = (const int4*)wh;
        int4* dst = (int4*)sW;
#pragma unroll
        for (int i = 0; i < 4; ++i) dst[t + 256 * i] = src[t + 256 * i];
    }
    __syncthreads();   // the only barrier

    const int lane = t & 63;
    const int wave = t >> 6;
    const int q = lane >> 4;        // quad 0..3
    const int m = lane & 15;        // edge-in-tile / w column
    const int v0 = (q & 1) * 8;

    const h16x8* gw = ((const h16x8*)wh) + 1024;   // paths {4,0,3} in global

    const int gw_id = blockIdx.x * 4 + wave;
    const int nw = gridDim.x * 4;
    int tile = (int)(((long long)gw_id * N_TILES) / nw);
    const int tileEnd = (int)(((long long)(gw_id + 1) * N_TILES) / nw);
    if (tile >= tileEnd) return;

    int rc = sortedRC[tile * 16 + m];
    h16x4 Bt[8];
    {
        const h16x4* bp = feat + (size_t)(((unsigned)rc) >> 16) * 16 + v0;
#pragma unroll
        for (int k = 0; k < 8; ++k) Bt[k] = bp[k];
    }

    for (; tile < tileEnd; ++tile) {
        const int myR = rc & 0xFFFF;
        const int nt = tile + 1;
        const int nrc = (nt < tileEnd) ? sortedRC[nt * 16 + m] : rc;

        // transpose gathered B into packed-f16 v-pairs (Bt dies here)
        h16x2 Bs[4], Bx[4], By[4], Bz[4];
#pragma unroll
        for (int k = 0; k < 4; ++k) {
            Bs[k].x = Bt[2 * k].x; Bs[k].y = Bt[2 * k + 1].x;
            Bx[k].x = Bt[2 * k].y; Bx[k].y = Bt[2 * k + 1].y;
            By[k].x = Bt[2 * k].z; By[k].y = Bt[2 * k + 1].z;
            Bz[k].x = Bt[2 * k].w; Bz[k].y = Bt[2 * k + 1].w;
        }

        f32x4 acc_s = {0.f, 0.f, 0.f, 0.f};
        f32x4 acc_x = {0.f, 0.f, 0.f, 0.f};
        f32x4 acc_y = {0.f, 0.f, 0.f, 0.f};
        f32x4 acc_z = {0.f, 0.f, 0.f, 0.f};

        const h16x4* ap = feat + (size_t)myR * 16;

#pragma unroll 4
        for (int c = 0; c < 8; ++c) {
            // global weight loads first (longest latency)
            short w4s = 0;   // placeholder to keep declaration order tight
            h16x8 w4f = gw[(0 * 8 + c) * 64 + lane];   // path 4 (cross)
            h16x8 w0f = gw[(1 * 8 + c) * 64 + lane];   // path 0 (ss)
            h16x8 w3f = gw[(2 * 8 + c) * 64 + lane];   // path 3 (dot)
            h16x8 w1f = sW[(0 * 8 + c) * 64 + lane];
            h16x8 w2f = sW[(1 * 8 + c) * 64 + lane];
            (void)w4s;

            h16x4 A = ap[2 * c + (q >> 1)];   // L1-hot (sorted rows)
            h16x2 s2; s2.x = A.x; s2.y = A.x;
            h16x2 x2; x2.x = A.y; x2.y = A.y;
            h16x2 y2; y2.x = A.z; y2.y = A.z;
            h16x2 z2; z2.x = A.w; z2.y = A.w;

            union { h16x8 v; h16x2 h[4]; } z;

            // ss = s1*s2 -> W0 (acc_s)
#pragma unroll
            for (int k = 0; k < 4; ++k) z.h[k] = s2 * Bs[k];
            acc_s = __builtin_amdgcn_mfma_f32_16x16x32_f16(z.v, w0f, acc_s, 0, 0, 0);

            // dot(v1,v2) -> W3 (acc_s)
#pragma unroll
            for (int k = 0; k < 4; ++k)
                z.h[k] = x2 * Bx[k] + y2 * By[k] + z2 * Bz[k];
            acc_s = __builtin_amdgcn_mfma_f32_16x16x32_f16(z.v, w3f, acc_s, 0, 0, 0);

            // s1*v2x -> W1 (acc_x)
#pragma unroll
            for (int k = 0; k < 4; ++k) z.h[k] = s2 * Bx[k];
            acc_x = __builtin_amdgcn_mfma_f32_16x16x32_f16(z.v, w1f, acc_x, 0, 0, 0);
            // v1x*s2 -> W2 (acc_x)
#pragma unroll
            for (int k = 0; k < 4; ++k) z.h[k] = x2 * Bs[k];
            acc_x = __builtin_amdgcn_mfma_f32_16x16x32_f16(z.v, w2f, acc_x, 0, 0, 0);
            // cross_x = v1y*v2z - v1z*v2y -> W4 (acc_x)
#pragma unroll
            for (int k = 0; k < 4; ++k) z.h[k] = y2 * Bz[k] - z2 * By[k];
            acc_x = __builtin_amdgcn_mfma_f32_16x16x32_f16(z.v, w4f, acc_x, 0, 0, 0);

            // s1*v2y -> W1 (acc_y)
#pragma unroll
            for (int k = 0; k < 4; ++k) z.h[k] = s2 * By[k];
            acc_y = __builtin_amdgcn_mfma_f32_16x16x32_f16(z.v, w1f, acc_y, 0, 0, 0);
            // v1y*s2 -> W2 (acc_y)
#pragma unroll
            for (int k = 0; k < 4; ++k) z.h[k] = y2 * Bs[k];
            acc_y = __builtin_amdgcn_mfma_f32_16x16x32_f16(z.v, w2f, acc_y, 0, 0, 0);
            // cross_y = v1z*v2x - v1x*v2z -> W4 (acc_y)
#pragma unroll
            for (int k = 0; k < 4; ++k) z.h[k] = z2 * Bx[k] - x2 * Bz[k];
            acc_y = __builtin_amdgcn_mfma_f32_16x16x32_f16(z.v, w4f, acc_y, 0, 0, 0);

            // s1*v2z -> W1 (acc_z)
#pragma unroll
            for (int k = 0; k < 4; ++k) z.h[k] = s2 * Bz[k];
            acc_z = __builtin_amdgcn_mfma_f32_16x16x32_f16(z.v, w1f, acc_z, 0, 0, 0);
            // v1z*s2 -> W2 (acc_z)
#pragma unroll
            for (int k = 0; k < 4; ++k) z.h[k] = z2 * Bs[k];
            acc_z = __builtin_amdgcn_mfma_f32_16x16x32_f16(z.v, w2f, acc_z, 0, 0, 0);
            // cross_z = v1x*v2y - v1y*v2x -> W4 (acc_z)
#pragma unroll
            for (int k = 0; k < 4; ++k) z.h[k] = x2 * By[k] - y2 * Bx[k];
            acc_z = __builtin_amdgcn_mfma_f32_16x16x32_f16(z.v, w4f, acc_z, 0, 0, 0);
        }

        // prefetch next tile's B into Bt AFTER the chunk loop
        {
            const h16x4* nbp = feat + (size_t)(((unsigned)nrc) >> 16) * 16 + v0;
#pragma unroll
            for (int k = 0; k < 8; ++k) Bt[k] = nbp[k];
        }

        // ---------- wave-local segmented epilogue (shuffle reduction) ----------
        int prevR = __shfl(myR, (lane + 63) & 63);
        int flag = (m == 0) || (myR != prevR);
        unsigned long long bal = __ballot(flag != 0);
        unsigned mask16 = (unsigned)(bal & 0xFFFFull);   // identical across quads

        int nseg = __popc(mask16);
        unsigned rem = mask16;
        for (int s = 0; s < nseg; ++s) {
            int lo = __ffs(rem) - 1;
            rem &= rem - 1;
            int hi = rem ? (__ffs(rem) - 1) : 16;
            float ps = 0.f, px = 0.f, py = 0.f, pz = 0.f;
#pragma unroll
            for (int r = 0; r < 4; ++r) {
                int ei = q * 4 + r;
                bool in = (ei >= lo) && (ei < hi);
                ps += in ? acc_s[r] : 0.f;
                px += in ? acc_x[r] : 0.f;
                py += in ? acc_y[r] : 0.f;
                pz += in ? acc_z[r] : 0.f;
            }
            ps += __shfl_xor(ps, 16); ps += __shfl_xor(ps, 32);
            px += __shfl_xor(px, 16); px += __shfl_xor(px, 32);
            py += __shfl_xor(py, 16); py += __shfl_xor(py, 32);
            pz += __shfl_xor(pz, 16); pz += __shfl_xor(pz, 32);
            int node = __shfl(myR, lo);
            float val = (q == 0) ? ps : (q == 1) ? px : (q == 2) ? py : pz;
            atomicAdd(out + (size_t)node * 64 + m * 4 + q, val);
        }

        rc = nrc;
    }
}

// -------------------- gate acc -> fp16 features (pre-scaled by ALPHA) + zero acc
__global__ void gate_half_kernel(float4* __restrict__ acc,
                                 h16x4* __restrict__ featH) {
    int i = blockIdx.x * 256 + threadIdx.x;   // (n*16 + w)
    if (i >= N_NODES * 16) return;
    float4 f = acc[i];
    float g = ALPHA / (1.f + __expf(-f.x));   // sigmoid * feature pre-scale
    h16x4 o;
    o.x = (_Float16)(f.x * g);
    o.y = (_Float16)(f.y * g);
    o.z = (_Float16)(f.z * g);
    o.w = (_Float16)(f.w * g);
    featH[i] = o;
    acc[i] = make_float4(0.f, 0.f, 0.f, 0.f);
}

// -------------------- final gate + readout fused (reads f32 acc)
__global__ void gate_readout_kernel(const float4* __restrict__ feat,
                                    const int* __restrict__ batch_idx,
                                    const float* __restrict__ w_out,
                                    float* __restrict__ energy) {
    __shared__ float bins[N_GRAPHS];
    int t = threadIdx.x;
    if (t < N_GRAPHS) bins[t] = 0.f;
    __syncthreads();
    int n = blockIdx.x * 256 + t;
    if (n < N_NODES) {
        const float4* f = feat + (size_t)n * 16;
        float acc = 0.f;
#pragma unroll
        for (int w = 0; w < 16; ++w) {
            float s = f[w].x;
            float silu = s / (1.f + __expf(-s));
            acc += silu * w_out[w];
        }
        atomicAdd(&bins[batch_idx[n]], acc * INV_LIN_OUT);
    }
    __syncthreads();
    if (t < N_GRAPHS) atomicAdd(&energy[t], bins[t]);
}

extern "C" void kernel_launch(void* const* d_in, const int* in_sizes, int n_in,
                              void* d_out, int out_size, void* d_ws, size_t ws_size,
                              hipStream_t stream) {
    const float* x         = (const float*)d_in[0];
    const int*   row       = (const int*)d_in[1];
    const int*   col       = (const int*)d_in[2];
    const int*   batch_idx = (const int*)d_in[3];
    const float* w_in0     = (const float*)d_in[4];
    const float* w_in1     = (const float*)d_in[5];
    const float* tp_w      = (const float*)d_in[6];   // [3][5][16][16][16]
    const float* w_out0    = (const float*)d_in[7];
    float* energy = (float*)d_out;

    // workspace layout (28.1 MB total)
    float*    acc   = (float*)d_ws;                        // [N][64] f32 accum
    _Float16* featA = (_Float16*)(acc + (size_t)N_NODES * 64);   // [N][64] f16
    _Float16* featB = featA + (size_t)N_NODES * 64;              // [N][64] f16
    _Float16* wh    = featB + (size_t)N_NODES * 64;              // [3][20480] f16
    int* sortedRC = (int*)(wh + 3 * 20480);                // [E] packed (row | col<<16)
    // transient sort scratch aliased into featB (dead until layer-1 gate writes it)
    int* counts  = (int*)featB;
    int* cursor  = counts + N_NODES;
    int* partial = cursor + N_NODES;

    // fused init: proj -> featA (fp16), swizzle -> wh (fp16), zero counts/energy/acc
    init_kernel<<<(3 * 20480 + 255) / 256, 256, 0, stream>>>(
        x, w_in0, w_in1, tp_w, (h16x4*)featA, wh, counts, energy, (float4*)acc);

    // build destination-sorted edge list (4 dispatches)
    hist_kernel<<<(N_EDGES + 255) / 256, 256, 0, stream>>>(row, counts);
    scan_part_kernel<<<NPART, 256, 0, stream>>>(counts, partial);
    scan_final_kernel<<<NPART, 256, 0, stream>>>(counts, partial, cursor);
    scatter_kernel<<<(N_EDGES + 255) / 256, 256, 0, stream>>>(row, col, cursor, sortedRC);

    _Float16* fin = featA;
    _Float16* fnext = featB;
    for (int l = 0; l < 3; ++l) {
        edge_tp_kernel<<<EDGE_GRID, 256, 0, stream>>>(
            (const h16x4*)fin, acc, sortedRC, wh + (size_t)l * 20480);
        if (l < 2) {
            // gate acc -> fp16 features (x ALPHA) for next layer; re-zero acc
            gate_half_kernel<<<(N_NODES * 16 + 255) / 256, 256, 0, stream>>>(
                (float4*)acc, (h16x4*)fnext);
            _Float16* tmp = fin; fin = fnext; fnext = tmp;
        } else {
            gate_readout_kernel<<<(N_NODES + 255) / 256, 256, 0, stream>>>(
                (const float4*)acc, batch_idx, w_out0, energy);
        }
    }
}

// Round 4
// 433.050 us; speedup vs baseline: 1.1147x; 1.1147x over previous
//
#include <hip/hip_runtime.h>

#define N_NODES 50000
#define N_EDGES 600000
#define N_GRAPHS 64
#define N_TILES (N_EDGES / 16)   // 37500 wave-tiles
#define NPART 196                // ceil(50000/256) scan partials
#define EDGE_GRID 2048           // 8 blocks/CU target (16KB LDS, <=64 VGPR)

// constants
#define INV_LIN_IN  0.35355339059327373f   // 1/sqrt(8)
#define INV_LIN_OUT 0.25f                  // 1/sqrt(16)
#define C_INV_S3    0.5773502691896258f    // 1/sqrt(3)
#define C_INV_S2    0.7071067811865476f    // 1/sqrt(2)
#define C_NORM_S    0.04419417382415922f   // 1/sqrt(512)
#define C_NORM_V    0.036084391824351615f  // 1/sqrt(768)

// fp16 overflow guard: features entering layers 1,2 are scaled by ALPHA after
// the gate; the inverse (1/ALPHA^2 = 1024) is folded into those layers' weights.
// TP is bilinear so this is exact. Keeps layer-3 fp16 products ~56 max vs 65504.
#define ALPHA      0.03125f                // 1/32
#define W_UNSCALE  1024.0f                 // 1/ALPHA^2

typedef __attribute__((ext_vector_type(8))) _Float16 h16x8;
typedef __attribute__((ext_vector_type(4))) _Float16 h16x4;
typedef __attribute__((ext_vector_type(2))) _Float16 h16x2;
typedef __attribute__((ext_vector_type(4))) float f32x4;

// ==================== sort edges by destination (row); pack (row,col) in one int ====
__global__ void hist_kernel(const int* __restrict__ row, int* __restrict__ counts) {
    int e = blockIdx.x * 256 + threadIdx.x;
    if (e < N_EDGES) atomicAdd(&counts[row[e]], 1);
}

__global__ void scan_part_kernel(const int* __restrict__ counts, int* __restrict__ partial) {
    __shared__ int sm[256];
    int t = threadIdx.x;
    int i = blockIdx.x * 256 + t;
    sm[t] = (i < N_NODES) ? counts[i] : 0;
    __syncthreads();
    for (int s = 128; s > 0; s >>= 1) {
        if (t < s) sm[t] += sm[t + s];
        __syncthreads();
    }
    if (t == 0) partial[blockIdx.x] = sm[0];
}

// scan_final with the partial-prefix folded in (replaces scan_partials_kernel):
// each block reduces partial[0..blockIdx) in a second shared array.
__global__ void scan_final_kernel(const int* __restrict__ counts,
                                  const int* __restrict__ partial,
                                  int* __restrict__ cursor) {
    __shared__ int sm[256];
    __shared__ int sm2[256];
    int t = threadIdx.x;
    int i = blockIdx.x * 256 + t;
    int v = (i < N_NODES) ? counts[i] : 0;
    sm[t] = v;
    sm2[t] = (t < NPART && t < blockIdx.x) ? partial[t] : 0;
    __syncthreads();
    // tree-reduce sm2 -> sum of partial[0..blockIdx)
    for (int s = 128; s > 0; s >>= 1) {
        if (t < s) sm2[t] += sm2[t + s];
        __syncthreads();
    }
    int base = sm2[0];
    // inclusive scan of counts within block
    for (int s = 1; s < 256; s <<= 1) {
        int add = (t >= s) ? sm[t - s] : 0;
        __syncthreads();
        sm[t] += add;
        __syncthreads();
    }
    if (i < N_NODES) cursor[i] = sm[t] - v + base;   // exclusive offsets
}

__global__ void scatter_kernel(const int* __restrict__ row, const int* __restrict__ col,
                               int* __restrict__ cursor, int* __restrict__ sortedRC) {
    int e = blockIdx.x * 256 + threadIdx.x;
    if (e < N_EDGES) {
        int n = row[e];
        int pos = atomicAdd(&cursor[n], 1);
        sortedRC[pos] = n | (col[e] << 16);   // node ids < 50000 < 65536
    }
}

// -------------------- fused init: proj (fp16 out) + weight swizzle (fp16) +
// counts-zero + energy-zero + acc-zero (replaces hipMemsetAsync)
__global__ void init_kernel(const float* __restrict__ x,
                            const float* __restrict__ w_in0,
                            const float* __restrict__ w_in1,
                            const float* __restrict__ tp_w,
                            h16x4* __restrict__ featH,
                            _Float16* __restrict__ wh,
                            int* __restrict__ counts,
                            float* __restrict__ energy,
                            float4* __restrict__ acc) {
    int gid = blockIdx.x * 256 + threadIdx.x;

    if (gid < 64) energy[gid] = 0.f;
    if (gid < N_NODES) counts[gid] = 0;

    // zero the f32 accumulator: 800k float4 over 61440 threads (grid-stride)
    for (int idx = gid; idx < N_NODES * 16; idx += 61440)
        acc[idx] = make_float4(0.f, 0.f, 0.f, 0.f);

    if (gid < 3 * 20480) {   // weight swizzle -> fp16 (one-time cost)
        int i = gid;
        int j    = i & 7;
        int t1   = i >> 3;
        int lane = t1 & 63;
        int t2   = t1 >> 6;
        int c    = t2 & 7;
        int t3   = t2 >> 3;
        int slot = t3 % 5;
        int l    = t3 / 5;
        int p = (slot == 0) ? 1 : (slot == 1) ? 2 : (slot == 2) ? 4 : (slot == 3) ? 0 : 3;
        int kk = c * 32 + (lane >> 4) * 8 + j;
        int u = kk >> 4, v = kk & 15, n = lane & 15;
        float scale;
        if      (p == 0) scale = C_NORM_S;
        else if (p == 3) scale = C_INV_S3 * C_NORM_S;
        else if (p == 4) scale = C_INV_S2 * C_NORM_V;
        else             scale = C_NORM_V;   // p==1, p==2
        if (l > 0) scale *= W_UNSCALE;       // undo ALPHA^2 feature pre-scale
        float val = tp_w[(size_t)(l * 5 + p) * 4096 + u * 256 + v * 16 + n] * scale;
        wh[i] = (_Float16)val;
    }

    if (gid < N_NODES) {     // input projection -> fp16 features (layer-0: unscaled)
        const float* xp = x + (size_t)gid * 32;
        float xs[8], xvx[8], xvy[8], xvz[8];
#pragma unroll
        for (int u = 0; u < 8; ++u) xs[u] = xp[u];
#pragma unroll
        for (int u = 0; u < 8; ++u) {
            xvx[u] = xp[8 + 3 * u + 0];
            xvy[u] = xp[8 + 3 * u + 1];
            xvz[u] = xp[8 + 3 * u + 2];
        }
#pragma unroll
        for (int w = 0; w < 16; ++w) {
            float s = 0.f, vx = 0.f, vy = 0.f, vz = 0.f;
#pragma unroll
            for (int u = 0; u < 8; ++u) {
                float a0 = w_in0[u * 16 + w];
                float a1 = w_in1[u * 16 + w];
                s  += xs[u]  * a0;
                vx += xvx[u] * a1;
                vy += xvy[u] * a1;
                vz += xvz[u] * a1;
            }
            h16x4 o;
            o.x = (_Float16)(s  * INV_LIN_IN);
            o.y = (_Float16)(vx * INV_LIN_IN);
            o.z = (_Float16)(vy * INV_LIN_IN);
            o.w = (_Float16)(vz * INV_LIN_IN);
            featH[(size_t)gid * 16 + w] = o;
        }
    }
}

// -------------------- edge tensor product (fp16): persistent waves, W1/W2 in
// LDS (16KB), W4/W0/W3 from global (L1-hot); z-formation fully in packed
// v_pk_*_f16; unroll 4 for the load-hoisting window.
// launch_bounds(256,4): guarantee 4 blocks/CU WITHOUT a hard reg cap —
// R3's (256,8) forced VGPR<=64 -> scratch spills (+168MB HBM/dispatch).
// Natural reg use ~52-64 -> 8 blocks/CU via the 64-VGPR occupancy granule.
__global__ __launch_bounds__(256, 4)
void edge_tp_kernel(const h16x4* __restrict__ feat,
                    float* __restrict__ out,          // [N][16][4] f32 accum
                    const int* __restrict__ sortedRC,
                    const _Float16* __restrict__ wh) {
    __shared__ h16x8 sW[1024];   // 16 KB: paths {1,2}

    const int t = threadIdx.x;
    {
        const int4* src = (const int4*)wh;
        int4* dst = (int4*)sW;
#pragma unroll
        for (int i = 0; i < 4; ++i) dst[t + 256 * i] = src[t + 256 * i];
    }
    __syncthreads();   // the only barrier

    const int lane = t & 63;
    const int wave = t >> 6;
    const int q = lane >> 4;        // quad 0..3
    const int m = lane & 15;        // edge-in-tile / w column
    const int v0 = (q & 1) * 8;

    const h16x8* gw = ((const h16x8*)wh) + 1024;   // paths {4,0,3} in global

    const int gw_id = blockIdx.x * 4 + wave;
    const int nw = gridDim.x * 4;
    int tile = (int)(((long long)gw_id * N_TILES) / nw);
    const int tileEnd = (int)(((long long)(gw_id + 1) * N_TILES) / nw);
    if (tile >= tileEnd) return;

    int rc = sortedRC[tile * 16 + m];
    h16x4 Bt[8];
    {
        const h16x4* bp = feat + (size_t)(((unsigned)rc) >> 16) * 16 + v0;
#pragma unroll
        for (int k = 0; k < 8; ++k) Bt[k] = bp[k];
    }

    for (; tile < tileEnd; ++tile) {
        const int myR = rc & 0xFFFF;
        const int nt = tile + 1;
        const int nrc = (nt < tileEnd) ? sortedRC[nt * 16 + m] : rc;

        // transpose gathered B into packed-f16 v-pairs (Bt dies here)
        h16x2 Bs[4], Bx[4], By[4], Bz[4];
#pragma unroll
        for (int k = 0; k < 4; ++k) {
            Bs[k].x = Bt[2 * k].x; Bs[k].y = Bt[2 * k + 1].x;
            Bx[k].x = Bt[2 * k].y; Bx[k].y = Bt[2 * k + 1].y;
            By[k].x = Bt[2 * k].z; By[k].y = Bt[2 * k + 1].z;
            Bz[k].x = Bt[2 * k].w; Bz[k].y = Bt[2 * k + 1].w;
        }

        f32x4 acc_s = {0.f, 0.f, 0.f, 0.f};
        f32x4 acc_x = {0.f, 0.f, 0.f, 0.f};
        f32x4 acc_y = {0.f, 0.f, 0.f, 0.f};
        f32x4 acc_z = {0.f, 0.f, 0.f, 0.f};

        const h16x4* ap = feat + (size_t)myR * 16;

#pragma unroll 4
        for (int c = 0; c < 8; ++c) {
            // global weight loads first (longest latency)
            h16x8 w4f = gw[(0 * 8 + c) * 64 + lane];   // path 4 (cross)
            h16x8 w0f = gw[(1 * 8 + c) * 64 + lane];   // path 0 (ss)
            h16x8 w3f = gw[(2 * 8 + c) * 64 + lane];   // path 3 (dot)
            h16x8 w1f = sW[(0 * 8 + c) * 64 + lane];
            h16x8 w2f = sW[(1 * 8 + c) * 64 + lane];

            h16x4 A = ap[2 * c + (q >> 1)];   // L1-hot (sorted rows)
            h16x2 s2; s2.x = A.x; s2.y = A.x;
            h16x2 x2; x2.x = A.y; x2.y = A.y;
            h16x2 y2; y2.x = A.z; y2.y = A.z;
            h16x2 z2; z2.x = A.w; z2.y = A.w;

            union { h16x8 v; h16x2 h[4]; } z;

            // ss = s1*s2 -> W0 (acc_s)
#pragma unroll
            for (int k = 0; k < 4; ++k) z.h[k] = s2 * Bs[k];
            acc_s = __builtin_amdgcn_mfma_f32_16x16x32_f16(z.v, w0f, acc_s, 0, 0, 0);

            // dot(v1,v2) -> W3 (acc_s)
#pragma unroll
            for (int k = 0; k < 4; ++k)
                z.h[k] = x2 * Bx[k] + y2 * By[k] + z2 * Bz[k];
            acc_s = __builtin_amdgcn_mfma_f32_16x16x32_f16(z.v, w3f, acc_s, 0, 0, 0);

            // s1*v2x -> W1 (acc_x)
#pragma unroll
            for (int k = 0; k < 4; ++k) z.h[k] = s2 * Bx[k];
            acc_x = __builtin_amdgcn_mfma_f32_16x16x32_f16(z.v, w1f, acc_x, 0, 0, 0);
            // v1x*s2 -> W2 (acc_x)
#pragma unroll
            for (int k = 0; k < 4; ++k) z.h[k] = x2 * Bs[k];
            acc_x = __builtin_amdgcn_mfma_f32_16x16x32_f16(z.v, w2f, acc_x, 0, 0, 0);
            // cross_x = v1y*v2z - v1z*v2y -> W4 (acc_x)
#pragma unroll
            for (int k = 0; k < 4; ++k) z.h[k] = y2 * Bz[k] - z2 * By[k];
            acc_x = __builtin_amdgcn_mfma_f32_16x16x32_f16(z.v, w4f, acc_x, 0, 0, 0);

            // s1*v2y -> W1 (acc_y)
#pragma unroll
            for (int k = 0; k < 4; ++k) z.h[k] = s2 * By[k];
            acc_y = __builtin_amdgcn_mfma_f32_16x16x32_f16(z.v, w1f, acc_y, 0, 0, 0);
            // v1y*s2 -> W2 (acc_y)
#pragma unroll
            for (int k = 0; k < 4; ++k) z.h[k] = y2 * Bs[k];
            acc_y = __builtin_amdgcn_mfma_f32_16x16x32_f16(z.v, w2f, acc_y, 0, 0, 0);
            // cross_y = v1z*v2x - v1x*v2z -> W4 (acc_y)
#pragma unroll
            for (int k = 0; k < 4; ++k) z.h[k] = z2 * Bx[k] - x2 * Bz[k];
            acc_y = __builtin_amdgcn_mfma_f32_16x16x32_f16(z.v, w4f, acc_y, 0, 0, 0);

            // s1*v2z -> W1 (acc_z)
#pragma unroll
            for (int k = 0; k < 4; ++k) z.h[k] = s2 * Bz[k];
            acc_z = __builtin_amdgcn_mfma_f32_16x16x32_f16(z.v, w1f, acc_z, 0, 0, 0);
            // v1z*s2 -> W2 (acc_z)
#pragma unroll
            for (int k = 0; k < 4; ++k) z.h[k] = z2 * Bs[k];
            acc_z = __builtin_amdgcn_mfma_f32_16x16x32_f16(z.v, w2f, acc_z, 0, 0, 0);
            // cross_z = v1x*v2y - v1y*v2x -> W4 (acc_z)
#pragma unroll
            for (int k = 0; k < 4; ++k) z.h[k] = x2 * By[k] - y2 * Bx[k];
            acc_z = __builtin_amdgcn_mfma_f32_16x16x32_f16(z.v, w4f, acc_z, 0, 0, 0);
        }

        // prefetch next tile's B into Bt AFTER the chunk loop
        {
            const h16x4* nbp = feat + (size_t)(((unsigned)nrc) >> 16) * 16 + v0;
#pragma unroll
            for (int k = 0; k < 8; ++k) Bt[k] = nbp[k];
        }

        // ---------- wave-local segmented epilogue (shuffle reduction) ----------
        int prevR = __shfl(myR, (lane + 63) & 63);
        int flag = (m == 0) || (myR != prevR);
        unsigned long long bal = __ballot(flag != 0);
        unsigned mask16 = (unsigned)(bal & 0xFFFFull);   // identical across quads

        int nseg = __popc(mask16);
        unsigned rem = mask16;
        for (int s = 0; s < nseg; ++s) {
            int lo = __ffs(rem) - 1;
            rem &= rem - 1;
            int hi = rem ? (__ffs(rem) - 1) : 16;
            float ps = 0.f, px = 0.f, py = 0.f, pz = 0.f;
#pragma unroll
            for (int r = 0; r < 4; ++r) {
                int ei = q * 4 + r;
                bool in = (ei >= lo) && (ei < hi);
                ps += in ? acc_s[r] : 0.f;
                px += in ? acc_x[r] : 0.f;
                py += in ? acc_y[r] : 0.f;
                pz += in ? acc_z[r] : 0.f;
            }
            ps += __shfl_xor(ps, 16); ps += __shfl_xor(ps, 32);
            px += __shfl_xor(px, 16); px += __shfl_xor(px, 32);
            py += __shfl_xor(py, 16); py += __shfl_xor(py, 32);
            pz += __shfl_xor(pz, 16); pz += __shfl_xor(pz, 32);
            int node = __shfl(myR, lo);
            float val = (q == 0) ? ps : (q == 1) ? px : (q == 2) ? py : pz;
            atomicAdd(out + (size_t)node * 64 + m * 4 + q, val);
        }

        rc = nrc;
    }
}

// -------------------- gate acc -> fp16 features (pre-scaled by ALPHA) + zero acc
__global__ void gate_half_kernel(float4* __restrict__ acc,
                                 h16x4* __restrict__ featH) {
    int i = blockIdx.x * 256 + threadIdx.x;   // (n*16 + w)
    if (i >= N_NODES * 16) return;
    float4 f = acc[i];
    float g = ALPHA / (1.f + __expf(-f.x));   // sigmoid * feature pre-scale
    h16x4 o;
    o.x = (_Float16)(f.x * g);
    o.y = (_Float16)(f.y * g);
    o.z = (_Float16)(f.z * g);
    o.w = (_Float16)(f.w * g);
    featH[i] = o;
    acc[i] = make_float4(0.f, 0.f, 0.f, 0.f);
}

// -------------------- final gate + readout fused (reads f32 acc)
__global__ void gate_readout_kernel(const float4* __restrict__ feat,
                                    const int* __restrict__ batch_idx,
                                    const float* __restrict__ w_out,
                                    float* __restrict__ energy) {
    __shared__ float bins[N_GRAPHS];
    int t = threadIdx.x;
    if (t < N_GRAPHS) bins[t] = 0.f;
    __syncthreads();
    int n = blockIdx.x * 256 + t;
    if (n < N_NODES) {
        const float4* f = feat + (size_t)n * 16;
        float acc = 0.f;
#pragma unroll
        for (int w = 0; w < 16; ++w) {
            float s = f[w].x;
            float silu = s / (1.f + __expf(-s));
            acc += silu * w_out[w];
        }
        atomicAdd(&bins[batch_idx[n]], acc * INV_LIN_OUT);
    }
    __syncthreads();
    if (t < N_GRAPHS) atomicAdd(&energy[t], bins[t]);
}

extern "C" void kernel_launch(void* const* d_in, const int* in_sizes, int n_in,
                              void* d_out, int out_size, void* d_ws, size_t ws_size,
                              hipStream_t stream) {
    const float* x         = (const float*)d_in[0];
    const int*   row       = (const int*)d_in[1];
    const int*   col       = (const int*)d_in[2];
    const int*   batch_idx = (const int*)d_in[3];
    const float* w_in0     = (const float*)d_in[4];
    const float* w_in1     = (const float*)d_in[5];
    const float* tp_w      = (const float*)d_in[6];   // [3][5][16][16][16]
    const float* w_out0    = (const float*)d_in[7];
    float* energy = (float*)d_out;

    // workspace layout (28.1 MB total)
    float*    acc   = (float*)d_ws;                        // [N][64] f32 accum
    _Float16* featA = (_Float16*)(acc + (size_t)N_NODES * 64);   // [N][64] f16
    _Float16* featB = featA + (size_t)N_NODES * 64;              // [N][64] f16
    _Float16* wh    = featB + (size_t)N_NODES * 64;              // [3][20480] f16
    int* sortedRC = (int*)(wh + 3 * 20480);                // [E] packed (row | col<<16)
    // transient sort scratch aliased into featB (dead until layer-1 gate writes it)
    int* counts  = (int*)featB;
    int* cursor  = counts + N_NODES;
    int* partial = cursor + N_NODES;

    // fused init: proj -> featA (fp16), swizzle -> wh (fp16), zero counts/energy/acc
    init_kernel<<<(3 * 20480 + 255) / 256, 256, 0, stream>>>(
        x, w_in0, w_in1, tp_w, (h16x4*)featA, wh, counts, energy, (float4*)acc);

    // build destination-sorted edge list (4 dispatches)
    hist_kernel<<<(N_EDGES + 255) / 256, 256, 0, stream>>>(row, counts);
    scan_part_kernel<<<NPART, 256, 0, stream>>>(counts, partial);
    scan_final_kernel<<<NPART, 256, 0, stream>>>(counts, partial, cursor);
    scatter_kernel<<<(N_EDGES + 255) / 256, 256, 0, stream>>>(row, col, cursor, sortedRC);

    _Float16* fin = featA;
    _Float16* fnext = featB;
    for (int l = 0; l < 3; ++l) {
        edge_tp_kernel<<<EDGE_GRID, 256, 0, stream>>>(
            (const h16x4*)fin, acc, sortedRC, wh + (size_t)l * 20480);
        if (l < 2) {
            // gate acc -> fp16 features (x ALPHA) for next layer; re-zero acc
            gate_half_kernel<<<(N_NODES * 16 + 255) / 256, 256, 0, stream>>>(
                (float4*)acc, (h16x4*)fnext);
            _Float16* tmp = fin; fin = fnext; fnext = tmp;
        } else {
            gate_readout_kernel<<<(N_NODES + 255) / 256, 256, 0, stream>>>(
                (const float4*)acc, batch_idx, w_out0, energy);
        }
    }
}